// Round 16
// baseline (68.917 us; speedup 1.0000x reference)
//
#include <hip/hip_runtime.h>
#include <hip/hip_bf16.h>

typedef __attribute__((ext_vector_type(4))) float f32x4;
typedef __attribute__((ext_vector_type(8))) short s16x8;
typedef __attribute__((ext_vector_type(4))) short s16x4;

#define MFMA16(a, b, c) __builtin_amdgcn_mfma_f32_16x16x32_bf16(a, b, c, 0, 0, 0)

#define PLANE ((size_t)12845056)
#define QSCALE 0.17677669529663687f

// integer RNE -- k_prep only
__device__ __forceinline__ unsigned short f2bf(float f) {
  union { float f; unsigned u; } v; v.f = f;
  unsigned u = v.u;
  u += 0x7fff + ((u >> 16) & 1);   // RNE
  return (unsigned short)(u >> 16);
}
// compiler-native RNE conversion (hot path)
__device__ __forceinline__ unsigned short nf2bf(float f) {
  __hip_bfloat16 h = __float2bfloat16(f);
  return *reinterpret_cast<unsigned short*>(&h);
}

typedef const __attribute__((address_space(1))) char gas_char;
typedef __attribute__((address_space(3))) char las_char;
__device__ __forceinline__ void gload_lds16(const void* g, void* l) {
  __builtin_amdgcn_global_load_lds((gas_char*)g, (las_char*)l, 16, 0, 0);
}

// ---------------------------------------------------------------------------
// Prepass (unchanged from R15).  W2F fragment order (jg 0..7 spans all 128
// permuted cols); W3 XOR-swizzled permuted; BIASA MFMA-C layout.
// ---------------------------------------------------------------------------
__global__ void k_prep(const float* __restrict__ QW, const float* __restrict__ OW,
                       const float* __restrict__ RPE,
                       unsigned short* __restrict__ W2F, unsigned short* __restrict__ W3,
                       float* __restrict__ BIASA) {
  const int b = blockIdx.x, t = threadIdx.x;
  if (b < 24) {                       // qkv_w -> fragment order
    const int e = (b * 256 + t) * 8;
    const int bi = e >> 9;            // (s*4+kc)*8 + jg
    const int l = (e >> 3) & 63;
    const int s = bi >> 5;
    const int kc = (bi >> 3) & 3;
    const int jg = bi & 7;
    const int li = l & 15, hi = l >> 4;
    const int c2 = ((jg >> 2) << 6) + li * 4 + (jg & 3);
    const int k0 = kc * 32 + hi * 8;
    const float sf = (s == 0) ? QSCALE : 1.0f;
    const float* src = QW + (size_t)(c2 * 3 + s) * 128 + k0;
#pragma unroll
    for (int q = 0; q < 8; ++q) W2F[e + q] = f2bf(src[q] * sf);
  } else if (b < 32) {                // out_w: 128*128, XOR-swizzled permuted
    const int e = ((b - 24) * 256 + t) * 8;
    const int sr = e >> 7;
    const int k0 = e & 127;
    const int c2 = (sr & 64) + (sr & 15) * 4 + ((sr >> 4) & 3);
    const float* src = OW + (size_t)c2 * 128 + k0;
    s16x8 h;
#pragma unroll
    for (int q = 0; q < 8; ++q) ((short*)&h)[q] = (short)f2bf(src[q]);
    *(s16x8*)((char*)(W3 + sr * 128) + ((k0 * 2) ^ ((sr & 7) << 4))) = h;
  } else {                            // bias tables in acc-fragment layout
    const int cl = b - 32;
    const int rm = cl >> 1, cm = cl & 1;
    for (int w = 0; w < 16; ++w) {
      const int idx = w * 256 + t;       // ((i*4+j)*64 + lane)*4 + rr
      const int rr = idx & 3;
      const int lane = (idx >> 2) & 63;
      const int ij = idx >> 8;
      const int q = (ij >> 2) * 16 + ((lane >> 4) & 3) * 4 + rr;
      const int k = (lane & 15) * 4 + (ij & 3);       // permuted-k mapping
      float v;
      if (q >= 49 || k >= 49) v = -1.0e30f;
      else {
        const int xq = q / 7, yq = q - xq * 7;
        const int xk = k / 7, yk = k - xk * 7;
        v = RPE[(xk - xq + 6) * 13 + (yk - yq + 6)];
        if (rm && ((xq >= 4) != (xk >= 4))) v = -1.0e30f;
        if (cm && (((yq == 4) && (yk < 4)) || ((yq < 4) && (yk >= 4)))) v = -1.0e30f;
      }
      BIASA[cl * 4096 + idx] = v;
    }
  }
}

// ---------------------------------------------------------------------------
// FUSED gemm_qkv + attention, ZERO-BARRIER wave-private design.
// One wave owns one window g = wb*4+wid end to end:
//   p_start = (49g)>>2, off = g&3; tokens t -> local slot u' = t+off (<52).
//   A-frags direct global (rows p_start+li, clamped), 3 FULL-WIDTH passes
//   (W2F jg 0..7) -> Q/K/V 16-row tiles in WAVE-PRIVATE LDS (12KB/wave);
//   attention reads with min(u',63) clamps; P (64x128B) overlays dead Q+K.
// No __syncthreads anywhere; per-wave LDS ops are in-order.  48KB/block ->
// 3 blocks/CU = 12 fully decoupled waves/CU.
// ---------------------------------------------------------------------------
__global__ __launch_bounds__(256, 3)
void k_fused(const float* __restrict__ X, const unsigned short* __restrict__ W2F,
             const float* __restrict__ B, const float* __restrict__ BIASA,
             unsigned short* __restrict__ AOUT) {
  __shared__ alignas(16) char LDS[49152];
  const int tid = threadIdx.x;
  const int bm = blockIdx.x;               // 0..2047
  const int n = bm >> 6;
  const int wb = bm & 63;
  const int lane = tid & 63, wid = tid >> 6;
  const int li = lane & 15, hi = lane >> 4;

  const int g = wb * 4 + wid;              // window 0..255 within n
  const int p_start = (49 * g) >> 2;
  const int off = g & 3;

  char* WQ = LDS + wid * 12288;            // 16 rows x 256B
  char* WK = WQ + 4096;
  char* WV = WQ + 8192;
  char* WP = WQ;                           // P overlays Q+K (64 rows x 128B)

  // bias for all 3 planes, full width: tile j -> col (j>>2)*64 + li*4 + (j&3)
  float bias[3][8];
#pragma unroll
  for (int s = 0; s < 3; ++s)
#pragma unroll
    for (int j = 0; j < 8; ++j) {
      const int c2 = ((j >> 2) << 6) + li * 4 + (j & 3);
      bias[s][j] = B[c2 * 3 + s] * ((s == 0) ? QSCALE : 1.0f);
    }

  // A-fragments direct from global (1 row-tile: row = p_start + li)
  s16x8 af[4];   // [kc]
  {
    int p = p_start + li;
    if (p > 3135) p = 3135;                    // clamp (outputs discarded)
    const int r_ = p / 56, c_ = p - r_ * 56;
    int ro = r_ + 4; if (ro >= 56) ro -= 56;   // roll(-4)
    int co = c_ + 4; if (co >= 56) co -= 56;
    const float* src = X + (((size_t)n * 3136 + ro * 56 + co) << 7) + hi * 8;
#pragma unroll
    for (int kc = 0; kc < 4; ++kc) {
      const f32x4 v0 = *(const f32x4*)(src + kc * 32);
      const f32x4 v1 = *(const f32x4*)(src + kc * 32 + 4);
      s16x8 h;
      h[0] = (short)nf2bf(v0.x); h[1] = (short)nf2bf(v0.y);
      h[2] = (short)nf2bf(v0.z); h[3] = (short)nf2bf(v0.w);
      h[4] = (short)nf2bf(v1.x); h[5] = (short)nf2bf(v1.y);
      h[6] = (short)nf2bf(v1.z); h[7] = (short)nf2bf(v1.w);
      af[kc] = h;
    }
  }

  // three full-width passes, wave-private outputs
#define FUSED_PASS(DSTP, S)                                                     \
  {                                                                             \
    f32x4 acc[8];                                                               \
    _Pragma("unroll")                                                           \
    for (int j = 0; j < 8; ++j) acc[j] = (f32x4){0.f, 0.f, 0.f, 0.f};           \
    _Pragma("unroll")                                                           \
    for (int kc = 0; kc < 4; ++kc) {                                            \
      s16x8 bfr[8];                                                             \
      _Pragma("unroll")                                                         \
      for (int j = 0; j < 8; ++j)                                               \
        bfr[j] = *(const s16x8*)(W2F + ((((S) * 4 + kc) * 8 + j) * 64 + lane) * 8); \
      _Pragma("unroll")                                                         \
      for (int j = 0; j < 8; ++j)                                               \
        acc[j] = MFMA16(af[kc], bfr[j], acc[j]);                                \
    }                                                                           \
    _Pragma("unroll")                                                           \
    for (int r = 0; r < 4; ++r) {                                               \
      const int row = hi * 4 + r;                                               \
      s16x4 h0, h1;                                                             \
      _Pragma("unroll")                                                         \
      for (int j = 0; j < 4; ++j) {                                             \
        h0[j] = (short)nf2bf(acc[j][r] + bias[S][j]);                           \
        h1[j] = (short)nf2bf(acc[j + 4][r] + bias[S][j + 4]);                   \
      }                                                                         \
      *(s16x4*)((DSTP) + row * 256 + ((li * 8) ^ ((row & 7) << 4))) = h0;       \
      *(s16x4*)((DSTP) + row * 256 + ((128 + li * 8) ^ ((row & 7) << 4))) = h1; \
    }                                                                           \
  }

  FUSED_PASS(WQ, 0)
  FUSED_PASS(WK, 1)
  FUSED_PASS(WV, 2)
#undef FUSED_PASS

  // ------------------------- attention (wave-private, no barrier) ----------
  const int wh = (g >> 3) & 7;
  const int ww = g & 7;
  const int cl = (wh == 7 ? 2 : 0) + (ww == 7 ? 1 : 0);
  const f32x4* bptr = (const f32x4*)(BIASA + (size_t)cl * 4096) + lane;

  // Q fragments (A-operand rows = tokens) / K (B-operand, permuted k=li*4+t)
  s16x8 qf[4], kf[4];
#pragma unroll
  for (int i = 0; i < 4; ++i) {
    int uq = i * 16 + li + off; if (uq > 63) uq = 63;
    const int pq = uq >> 2, cgq = uq & 3;
    qf[i] = *(const s16x8*)(WQ + pq * 256 + ((cgq * 64 + hi * 16) ^ ((pq & 7) << 4)));
    int uk = li * 4 + i + off; if (uk > 63) uk = 63;
    const int pk = uk >> 2, cgk = uk & 3;
    kf[i] = *(const s16x8*)(WK + pk * 256 + ((cgk * 64 + hi * 16) ^ ((pk & 7) << 4)));
  }

  f32x4 sc[4][4];
#pragma unroll
  for (int i = 0; i < 4; ++i)
#pragma unroll
    for (int j = 0; j < 4; ++j) sc[i][j] = bptr[(i * 4 + j) * 64];
#pragma unroll
  for (int i = 0; i < 4; ++i)
#pragma unroll
    for (int j = 0; j < 4; ++j)
      sc[i][j] = MFMA16(qf[i], kf[j], sc[i][j]);   // logits incl. bias+mask

  // softmax numerators -> P (overlays dead Q+K; same-wave in-order LDS)
#pragma unroll
  for (int i = 0; i < 4; ++i) {
#pragma unroll
    for (int r = 0; r < 4; ++r) {
      const int q = i * 16 + hi * 4 + r;
      if (q < 49) {
        s16x4 pb;
#pragma unroll
        for (int j = 0; j < 4; ++j)
          pb[j] = (short)nf2bf(__expf(sc[i][j][r]));
        *(s16x4*)(WP + q * 128 + ((li * 8) ^ ((q & 7) << 4))) = pb;
      }
    }
  }

  // V^T fragments: tile fn col li <-> d = li*2 + fn (token slots clamped)
  s16x8 vf[2][2];
#pragma unroll
  for (int kc = 0; kc < 2; ++kc)
#pragma unroll
    for (int fn = 0; fn < 2; ++fn) {
      s16x8 tv;
#pragma unroll
      for (int jj = 0; jj < 8; ++jj) {
        int u = kc * 32 + hi * 8 + jj + off; if (u > 63) u = 63;
        const int p = u >> 2, cg = u & 3;
        tv[jj] = *(const short*)(WV + p * 256 + ((cg * 64 + li * 4 + fn * 2) ^ ((p & 7) << 4)));
      }
      vf[kc][fn] = tv;
    }

  s16x8 ones;
#pragma unroll
  for (int e = 0; e < 8; ++e) ones[e] = (short)0x3F80;   // bf16 1.0

  const f32x4 zf = (f32x4){0.f, 0.f, 0.f, 0.f};
  f32x4 o[4][2], osum[4];
#pragma unroll
  for (int i = 0; i < 4; ++i) { o[i][0] = zf; o[i][1] = zf; osum[i] = zf; }
#pragma unroll
  for (int i = 0; i < 4; ++i) {
    const int row = i * 16 + li;
#pragma unroll
    for (int kc = 0; kc < 2; ++kc) {
      const s16x8 pf = *(const s16x8*)(WP + row * 128 + ((kc * 64 + hi * 16) ^ ((row & 7) << 4)));
      o[i][0] = MFMA16(pf, vf[kc][0], o[i][0]);
      o[i][1] = MFMA16(pf, vf[kc][1], o[i][1]);
      osum[i] = MFMA16(pf, ones, osum[i]);       // row sums, every lane
    }
  }

  unsigned short* obase = AOUT + (((size_t)(n * 12544 + g * 49)) << 5);
#pragma unroll
  for (int i = 0; i < 4; ++i)
#pragma unroll
    for (int r = 0; r < 4; ++r) {
      const int q = i * 16 + hi * 4 + r;
      if (q < 49) {
        const float ri = 1.0f / osum[i][r];
        const unsigned lo = nf2bf(o[i][0][r] * ri);          // d = li*2
        const unsigned hh = nf2bf(o[i][1][r] * ri);          // d = li*2+1
        *(unsigned*)((char*)obase + q * 64 + li * 4) = lo | (hh << 16);
      }
    }
}

// ---------------------------------------------------------------------------
// GEMM3 (unchanged; at HBM roofline).
// ---------------------------------------------------------------------------
__global__ __launch_bounds__(256, 3)
void k_gemm_out(const unsigned short* __restrict__ A, const unsigned short* __restrict__ W3,
                const float* __restrict__ B, float* __restrict__ OUT) {
  __shared__ unsigned short Alds[64 * 128];   // 16KB
  __shared__ unsigned short Blds[16384];      // 32KB
  const int tid = threadIdx.x;
  const int bm = blockIdx.x;                  // 0..1567
  const int lane = tid & 63, wid = tid >> 6;

  {
    const char* gb = (const char*)W3 + (wid << 13) + (lane << 4);
    char* lb = (char*)Blds + (wid << 13) + (lane << 4);
#pragma unroll
    for (int r = 0; r < 8; ++r) gload_lds16(gb + (r << 10), lb + (r << 10));
  }
#pragma unroll
  for (int c = 0; c < 4; ++c) {
    const int ofs = (wid << 12) + (c << 10) + (lane << 4);   // linear LDS dest byte
    const int rr = ofs >> 8;
    const int colb = ofs & 255;
    const int scol = colb ^ ((rr & 7) << 4);                 // inverse swizzle on source
    const int row = bm * 64 + rr;
    const int n = row / 3136;
    const int p = row - n * 3136;
    const int rf = p / 56, cf = p - rf * 56;
    int rs = rf + 53; if (rs >= 56) rs -= 56;                // roll(+3)
    int cs = cf + 53; if (cs >= 56) cs -= 56;
    const char* ga = (const char*)A + ((size_t)(n * 3136 + rs * 56 + cs)) * 256 + scol;
    gload_lds16(ga, (char*)Alds + ofs);
  }
  __syncthreads();

  const int li = lane & 15, hi = lane >> 4;
  const int rw = (wid >> 1) << 5, cw = (wid & 1) << 6;

  f32x4 acc[2][4];
#pragma unroll
  for (int i = 0; i < 2; ++i)
#pragma unroll
    for (int j = 0; j < 4; ++j) acc[i][j] = (f32x4){0.f, 0.f, 0.f, 0.f};

#pragma unroll
  for (int kc = 0; kc < 4; ++kc) {
    s16x8 af[2], bfr[4];
#pragma unroll
    for (int i = 0; i < 2; ++i) {
      const int ra = rw + i * 16 + li;
      af[i] = *(const s16x8*)((const char*)Alds + ra * 256 + ((kc * 64 + hi * 16) ^ ((ra & 7) << 4)));
    }
#pragma unroll
    for (int j = 0; j < 4; ++j) {
      const int cb = cw + j * 16 + li;
      bfr[j] = *(const s16x8*)((const char*)Blds + cb * 256 + ((kc * 64 + hi * 16) ^ ((cb & 7) << 4)));
    }
#pragma unroll
    for (int i = 0; i < 2; ++i)
#pragma unroll
      for (int j = 0; j < 4; ++j)
        acc[i][j] = MFMA16(af[i], bfr[j], acc[i][j]);
  }

  float bias4[4];
#pragma unroll
  for (int j = 0; j < 4; ++j) bias4[j] = B[cw + li * 4 + j];   // permuted cols
#pragma unroll
  for (int i = 0; i < 2; ++i)
#pragma unroll
    for (int r = 0; r < 4; ++r) {
      const int row = bm * 64 + rw + i * 16 + hi * 4 + r;
      f32x4 v;
#pragma unroll
      for (int j = 0; j < 4; ++j) v[j] = acc[i][j][r] + bias4[j];
      *(f32x4*)(OUT + (size_t)row * 128 + cw + li * 4) = v;
    }
}

extern "C" void kernel_launch(void* const* d_in, const int* in_sizes, int n_in,
                              void* d_out, int out_size, void* d_ws, size_t ws_size,
                              hipStream_t stream) {
  const float* x = (const float*)d_in[0];
  const float* qkv_w = (const float*)d_in[1];
  const float* qkv_b = (const float*)d_in[2];
  const float* out_w = (const float*)d_in[3];
  const float* out_b = (const float*)d_in[4];
  const float* rpe = (const float*)d_in[5];
  float* out = (float*)d_out;

  unsigned short* aout = (unsigned short*)d_ws;            // 1 plane (25.7 MB)
  unsigned short* W2F = aout + PLANE;                      // 49152 bf16 (frag order)
  unsigned short* W3 = W2F + 49152;                        // 16384 bf16
  float* BIASA = (float*)(W3 + 16384);                     // 4*4096 f32

  k_prep<<<36, 256, 0, stream>>>(qkv_w, out_w, rpe, W2F, W3, BIASA);
  k_fused<<<2048, 256, 0, stream>>>(x, W2F, qkv_b, BIASA, aout);
  k_gemm_out<<<1568, 256, 0, stream>>>(aout, W3, out_b, out);
}

// Round 17
// 62.194 us; speedup vs baseline: 1.1081x; 1.1081x over previous
//
#include <hip/hip_runtime.h>
#include <hip/hip_bf16.h>

typedef __attribute__((ext_vector_type(4))) float f32x4;
typedef __attribute__((ext_vector_type(8))) short s16x8;
typedef __attribute__((ext_vector_type(4))) short s16x4;

#define MFMA16(a, b, c) __builtin_amdgcn_mfma_f32_16x16x32_bf16(a, b, c, 0, 0, 0)

#define PLANE ((size_t)12845056)
#define QSCALE 0.17677669529663687f

// integer RNE -- k_prep only
__device__ __forceinline__ unsigned short f2bf(float f) {
  union { float f; unsigned u; } v; v.f = f;
  unsigned u = v.u;
  u += 0x7fff + ((u >> 16) & 1);   // RNE
  return (unsigned short)(u >> 16);
}
// compiler-native RNE conversion (hot path)
__device__ __forceinline__ unsigned short nf2bf(float f) {
  __hip_bfloat16 h = __float2bfloat16(f);
  return *reinterpret_cast<unsigned short*>(&h);
}

typedef const __attribute__((address_space(1))) char gas_char;
typedef __attribute__((address_space(3))) char las_char;
__device__ __forceinline__ void gload_lds16(const void* g, void* l) {
  __builtin_amdgcn_global_load_lds((gas_char*)g, (las_char*)l, 16, 0, 0);
}

// ---------------------------------------------------------------------------
// Prepass.  W2F fragment order; W3 XOR-swizzled permuted; BIASA MFMA-C layout.
// ---------------------------------------------------------------------------
__global__ void k_prep(const float* __restrict__ QW, const float* __restrict__ OW,
                       const float* __restrict__ RPE,
                       unsigned short* __restrict__ W2F, unsigned short* __restrict__ W3,
                       float* __restrict__ BIASA) {
  const int b = blockIdx.x, t = threadIdx.x;
  if (b < 24) {                       // qkv_w -> fragment order
    const int e = (b * 256 + t) * 8;
    const int bi = e >> 9;            // (s*4+kc)*8 + jg
    const int l = (e >> 3) & 63;
    const int s = bi >> 5;
    const int kc = (bi >> 3) & 3;
    const int jg = bi & 7;
    const int li = l & 15, hi = l >> 4;
    const int c2 = ((jg >> 2) << 6) + li * 4 + (jg & 3);
    const int k0 = kc * 32 + hi * 8;
    const float sf = (s == 0) ? QSCALE : 1.0f;
    const float* src = QW + (size_t)(c2 * 3 + s) * 128 + k0;
#pragma unroll
    for (int q = 0; q < 8; ++q) W2F[e + q] = f2bf(src[q] * sf);
  } else if (b < 32) {                // out_w: 128*128, XOR-swizzled permuted
    const int e = ((b - 24) * 256 + t) * 8;
    const int sr = e >> 7;
    const int k0 = e & 127;
    const int c2 = (sr & 64) + (sr & 15) * 4 + ((sr >> 4) & 3);
    const float* src = OW + (size_t)c2 * 128 + k0;
    s16x8 h;
#pragma unroll
    for (int q = 0; q < 8; ++q) ((short*)&h)[q] = (short)f2bf(src[q]);
    *(s16x8*)((char*)(W3 + sr * 128) + ((k0 * 2) ^ ((sr & 7) << 4))) = h;
  } else {                            // bias tables in acc-fragment layout
    const int cl = b - 32;
    const int rm = cl >> 1, cm = cl & 1;
    for (int w = 0; w < 16; ++w) {
      const int idx = w * 256 + t;       // ((i*4+j)*64 + lane)*4 + rr
      const int rr = idx & 3;
      const int lane = (idx >> 2) & 63;
      const int ij = idx >> 8;
      const int q = (ij >> 2) * 16 + ((lane >> 4) & 3) * 4 + rr;
      const int k = (lane & 15) * 4 + (ij & 3);       // permuted-k mapping
      float v;
      if (q >= 49 || k >= 49) v = -1.0e30f;
      else {
        const int xq = q / 7, yq = q - xq * 7;
        const int xk = k / 7, yk = k - xk * 7;
        v = RPE[(xk - xq + 6) * 13 + (yk - yq + 6)];
        if (rm && ((xq >= 4) != (xk >= 4))) v = -1.0e30f;
        if (cm && (((yq == 4) && (yk < 4)) || ((yq < 4) && (yk >= 4)))) v = -1.0e30f;
      }
      BIASA[cl * 4096 + idx] = v;
    }
  }
}

// ---------------------------------------------------------------------------
// FUSED gemm_qkv + attention (R15 structure = measured best, 63.4us) with
// T5 s_setprio(1) wrapped around the three MFMA clusters.  3 independent
// blocks/CU -> scheduler has staging-vs-MFMA wave diversity to arbitrate.
// LDS: A 49 rows @0, Q @12544, K @25088, V @37632 (56 rows, 49..55 zeroed)
//   = 51968 B -> 3 blocks/CU.  P reuses Q+K region (4 x 6272 = 25088).
// ---------------------------------------------------------------------------
#define A_OFF 0
#define Q_OFF 12544
#define K_OFF 25088
#define V_OFF 37632
#define PW_STR 6272

__global__ __launch_bounds__(256, 3)
void k_fused(const float* __restrict__ X, const unsigned short* __restrict__ W2F,
             const float* __restrict__ B, const float* __restrict__ BIASA,
             unsigned short* __restrict__ AOUT) {
  __shared__ alignas(16) char LDS[51968];
  const int tid = threadIdx.x;
  const int bm = blockIdx.x;               // 0..2047
  const int n = bm >> 6;
  const int wb = bm & 63;
  const int p0 = wb * 49;
  const int lane = tid & 63, wid = tid >> 6;
  const int li = lane & 15, hi = lane >> 4;
  const int rw = (wid >> 1) << 5;   // 0 or 32
  const int cw = (wid & 1) << 6;    // 0 or 64
  const int cwj = cw >> 4;          // 0 or 4 (jg base)

  // ---- A staging: coalesced (2 rows = 1KB dense per wave-instruction) ----
  {
    const int c16 = lane & 31;      // 16B chunk within 512B row
    const int rh = lane >> 5;       // 0/1: which of the 2 rows
#pragma unroll
    for (int i = 0; i < 7; ++i) {
      const int row = wid * 14 + i * 2 + rh;
      if (row < 49) {
        const int p = p0 + row;
        const int r_ = p / 56, c_ = p - r_ * 56;
        int ro = r_ + 4; if (ro >= 56) ro -= 56;   // roll(-4)
        int co = c_ + 4; if (co >= 56) co -= 56;
        const f32x4 v = *(const f32x4*)(X + (((size_t)n * 3136 + ro * 56 + co) << 7) + c16 * 4);
        s16x4 h;
        h[0] = (short)nf2bf(v.x); h[1] = (short)nf2bf(v.y);
        h[2] = (short)nf2bf(v.z); h[3] = (short)nf2bf(v.w);
        *(s16x4*)(LDS + A_OFF + row * 256 + ((c16 * 8) ^ ((row & 7) << 4))) = h;
      }
    }
  }

  // zero V pad rows 49..55 (read as t>=49 operands; must be finite)
  {
    const int off = tid * 8;
    if (off < 1792) *(double*)(LDS + V_OFF + 12544 + off) = 0.0;
  }

  // bias for all 3 planes at the PERMUTED logical cols cw + li*4 + j
  float bias[3][4];
#pragma unroll
  for (int s = 0; s < 3; ++s)
#pragma unroll
    for (int j = 0; j < 4; ++j)
      bias[s][j] = B[(cw + li * 4 + j) * 3 + s] * ((s == 0) ? QSCALE : 1.0f);

  __syncthreads();                  // A tile staged

  // A-fragments from LDS (pad rows clamped; their outputs are discarded)
  s16x8 af[4][2];   // [kc][i]
#pragma unroll
  for (int kc = 0; kc < 4; ++kc)
#pragma unroll
    for (int i = 0; i < 2; ++i) {
      int ra = rw + i * 16 + li;
      if (ra > 48) ra = 48;
      af[kc][i] = *(const s16x8*)(LDS + A_OFF + ra * 256 +
                                  ((kc * 64 + hi * 16) ^ ((ra & 7) << 4)));
    }

#define FUSED_PASS(DST, S)                                                      \
  {                                                                             \
    s16x8 bfr[4][4];                                                            \
    _Pragma("unroll")                                                           \
    for (int kc = 0; kc < 4; ++kc)                                              \
      _Pragma("unroll")                                                         \
      for (int j = 0; j < 4; ++j)                                               \
        bfr[kc][j] = *(const s16x8*)(W2F +                                      \
            ((((S) * 4 + kc) * 8 + cwj + j) * 64 + lane) * 8);                  \
    f32x4 acc[2][4];                                                            \
    _Pragma("unroll")                                                           \
    for (int i = 0; i < 2; ++i)                                                 \
      _Pragma("unroll")                                                         \
      for (int j = 0; j < 4; ++j) acc[i][j] = (f32x4){0.f, 0.f, 0.f, 0.f};      \
    __builtin_amdgcn_s_setprio(1);                                              \
    _Pragma("unroll")                                                           \
    for (int kc = 0; kc < 4; ++kc)                                              \
      _Pragma("unroll")                                                         \
      for (int i = 0; i < 2; ++i)                                               \
        _Pragma("unroll")                                                       \
        for (int j = 0; j < 4; ++j)                                             \
          acc[i][j] = MFMA16(af[kc][i], bfr[kc][j], acc[i][j]);                 \
    __builtin_amdgcn_s_setprio(0);                                              \
    _Pragma("unroll")                                                           \
    for (int i = 0; i < 2; ++i)                                                 \
      _Pragma("unroll")                                                         \
      for (int r = 0; r < 4; ++r) {                                             \
        const int row = rw + i * 16 + hi * 4 + r;                               \
        if (row < 49) {                                                         \
          s16x4 h;                                                              \
          _Pragma("unroll")                                                     \
          for (int j = 0; j < 4; ++j)                                           \
            h[j] = (short)nf2bf(acc[i][j][r] + bias[S][j]);                     \
          *(s16x4*)(LDS + (DST) + row * 256 +                                   \
                    ((cw * 2 + li * 8) ^ ((row & 7) << 4))) = h;                \
        }                                                                       \
      }                                                                         \
  }

  FUSED_PASS(Q_OFF, 0)
  FUSED_PASS(K_OFF, 1)
  FUSED_PASS(V_OFF, 2)
#undef FUSED_PASS

  __syncthreads();                  // Q/K/V (+ zeroed V pad) visible

  // ------------------------- attention (per wave) -------------------------
  const int g = wb * 4 + wid;              // window index within n, 0..255
  const int wh = (g >> 3) & 7;
  const int ww = g & 7;
  const int cl = (wh == 7 ? 2 : 0) + (ww == 7 ? 1 : 0);
  const f32x4* bptr = (const f32x4*)(BIASA + (size_t)cl * 4096) + lane;
  char* Pw = LDS + Q_OFF + wid * PW_STR;   // reuses dead Q/K region (after bar)
  const int uw = wid * 49;                 // wave's base u within block tile

  // Q fragments (A-operand) / K fragments (B-operand, PERMUTED k=li*4+t)
  s16x8 qf[4], kf[4];
#pragma unroll
  for (int i = 0; i < 4; ++i) {
    const int uq = uw + i * 16 + li;
    const int pq = uq >> 2, cgq = uq & 3;
    qf[i] = *(const s16x8*)(LDS + Q_OFF + pq * 256 + ((cgq * 64 + hi * 16) ^ ((pq & 7) << 4)));
    const int uk = uw + li * 4 + i;
    const int pk = uk >> 2, cgk = uk & 3;
    kf[i] = *(const s16x8*)(LDS + K_OFF + pk * 256 + ((cgk * 64 + hi * 16) ^ ((pk & 7) << 4)));
  }

  f32x4 sc[4][4];
#pragma unroll
  for (int i = 0; i < 4; ++i)
#pragma unroll
    for (int j = 0; j < 4; ++j) sc[i][j] = bptr[(i * 4 + j) * 64];
  __builtin_amdgcn_s_setprio(1);
#pragma unroll
  for (int i = 0; i < 4; ++i)
#pragma unroll
    for (int j = 0; j < 4; ++j)
      sc[i][j] = MFMA16(qf[i], kf[j], sc[i][j]);   // logits incl. bias+mask
  __builtin_amdgcn_s_setprio(0);

  __syncthreads();                  // all waves' Q/K reads done; region -> P

  // softmax numerators -> P (packed b64 writes, natural [q][k] layout)
#pragma unroll
  for (int i = 0; i < 4; ++i) {
#pragma unroll
    for (int r = 0; r < 4; ++r) {
      const int q = i * 16 + hi * 4 + r;
      if (q < 49) {
        s16x4 pb;
#pragma unroll
        for (int j = 0; j < 4; ++j)
          pb[j] = (short)nf2bf(__expf(sc[i][j][r]));
        *(s16x4*)(Pw + q * 128 + ((li * 8) ^ ((q & 7) << 4))) = pb;
      }
    }
  }

  // V^T fragments: tile fn col li <-> d = li*2 + fn (conflict-free gather)
  s16x8 vf[2][2];
#pragma unroll
  for (int kc = 0; kc < 2; ++kc)
#pragma unroll
    for (int fn = 0; fn < 2; ++fn) {
      s16x8 tv;
#pragma unroll
      for (int jj = 0; jj < 8; ++jj) {
        const int u = uw + kc * 32 + hi * 8 + jj;
        const int p = u >> 2, cg = u & 3;
        tv[jj] = *(const short*)(LDS + V_OFF + p * 256 + ((cg * 64 + li * 4 + fn * 2) ^ ((p & 7) << 4)));
      }
      vf[kc][fn] = tv;
    }

  s16x8 ones;
#pragma unroll
  for (int e = 0; e < 8; ++e) ones[e] = (short)0x3F80;   // bf16 1.0

  const f32x4 zf = (f32x4){0.f, 0.f, 0.f, 0.f};
  f32x4 o[4][2], osum[4];
#pragma unroll
  for (int i = 0; i < 4; ++i) { o[i][0] = zf; o[i][1] = zf; osum[i] = zf; }
  __builtin_amdgcn_s_setprio(1);
#pragma unroll
  for (int i = 0; i < 4; ++i) {
    const int row = i * 16 + li;
#pragma unroll
    for (int kc = 0; kc < 2; ++kc) {
      const s16x8 pf = *(const s16x8*)(Pw + row * 128 + ((kc * 64 + hi * 16) ^ ((row & 7) << 4)));
      o[i][0] = MFMA16(pf, vf[kc][0], o[i][0]);
      o[i][1] = MFMA16(pf, vf[kc][1], o[i][1]);
      osum[i] = MFMA16(pf, ones, osum[i]);       // row sums, every lane
    }
  }
  __builtin_amdgcn_s_setprio(0);

  unsigned short* obase = AOUT + (((size_t)(n * 12544 + g * 49)) << 5);
#pragma unroll
  for (int i = 0; i < 4; ++i)
#pragma unroll
    for (int r = 0; r < 4; ++r) {
      const int q = i * 16 + hi * 4 + r;
      if (q < 49) {
        const float ri = 1.0f / osum[i][r];
        const unsigned lo = nf2bf(o[i][0][r] * ri);          // d = li*2
        const unsigned hh = nf2bf(o[i][1][r] * ri);          // d = li*2+1
        *(unsigned*)((char*)obase + q * 64 + li * 4) = lo | (hh << 16);
      }
    }
}

// ---------------------------------------------------------------------------
// GEMM3 (unchanged; at HBM roofline).
// ---------------------------------------------------------------------------
__global__ __launch_bounds__(256, 3)
void k_gemm_out(const unsigned short* __restrict__ A, const unsigned short* __restrict__ W3,
                const float* __restrict__ B, float* __restrict__ OUT) {
  __shared__ unsigned short Alds[64 * 128];   // 16KB
  __shared__ unsigned short Blds[16384];      // 32KB
  const int tid = threadIdx.x;
  const int bm = blockIdx.x;                  // 0..1567
  const int lane = tid & 63, wid = tid >> 6;

  {
    const char* gb = (const char*)W3 + (wid << 13) + (lane << 4);
    char* lb = (char*)Blds + (wid << 13) + (lane << 4);
#pragma unroll
    for (int r = 0; r < 8; ++r) gload_lds16(gb + (r << 10), lb + (r << 10));
  }
#pragma unroll
  for (int c = 0; c < 4; ++c) {
    const int ofs = (wid << 12) + (c << 10) + (lane << 4);   // linear LDS dest byte
    const int rr = ofs >> 8;
    const int colb = ofs & 255;
    const int scol = colb ^ ((rr & 7) << 4);                 // inverse swizzle on source
    const int row = bm * 64 + rr;
    const int n = row / 3136;
    const int p = row - n * 3136;
    const int rf = p / 56, cf = p - rf * 56;
    int rs = rf + 53; if (rs >= 56) rs -= 56;                // roll(+3)
    int cs = cf + 53; if (cs >= 56) cs -= 56;
    const char* ga = (const char*)A + ((size_t)(n * 3136 + rs * 56 + cs)) * 256 + scol;
    gload_lds16(ga, (char*)Alds + ofs);
  }
  __syncthreads();

  const int li = lane & 15, hi = lane >> 4;
  const int rw = (wid >> 1) << 5, cw = (wid & 1) << 6;

  f32x4 acc[2][4];
#pragma unroll
  for (int i = 0; i < 2; ++i)
#pragma unroll
    for (int j = 0; j < 4; ++j) acc[i][j] = (f32x4){0.f, 0.f, 0.f, 0.f};

#pragma unroll
  for (int kc = 0; kc < 4; ++kc) {
    s16x8 af[2], bfr[4];
#pragma unroll
    for (int i = 0; i < 2; ++i) {
      const int ra = rw + i * 16 + li;
      af[i] = *(const s16x8*)((const char*)Alds + ra * 256 + ((kc * 64 + hi * 16) ^ ((ra & 7) << 4)));
    }
#pragma unroll
    for (int j = 0; j < 4; ++j) {
      const int cb = cw + j * 16 + li;
      bfr[j] = *(const s16x8*)((const char*)Blds + cb * 256 + ((kc * 64 + hi * 16) ^ ((cb & 7) << 4)));
    }
#pragma unroll
    for (int i = 0; i < 2; ++i)
#pragma unroll
      for (int j = 0; j < 4; ++j)
        acc[i][j] = MFMA16(af[i], bfr[j], acc[i][j]);
  }

  float bias4[4];
#pragma unroll
  for (int j = 0; j < 4; ++j) bias4[j] = B[cw + li * 4 + j];   // permuted cols
#pragma unroll
  for (int i = 0; i < 2; ++i)
#pragma unroll
    for (int r = 0; r < 4; ++r) {
      const int row = bm * 64 + rw + i * 16 + hi * 4 + r;
      f32x4 v;
#pragma unroll
      for (int j = 0; j < 4; ++j) v[j] = acc[i][j][r] + bias4[j];
      *(f32x4*)(OUT + (size_t)row * 128 + cw + li * 4) = v;
    }
}

extern "C" void kernel_launch(void* const* d_in, const int* in_sizes, int n_in,
                              void* d_out, int out_size, void* d_ws, size_t ws_size,
                              hipStream_t stream) {
  const float* x = (const float*)d_in[0];
  const float* qkv_w = (const float*)d_in[1];
  const float* qkv_b = (const float*)d_in[2];
  const float* out_w = (const float*)d_in[3];
  const float* out_b = (const float*)d_in[4];
  const float* rpe = (const float*)d_in[5];
  float* out = (float*)d_out;

  unsigned short* aout = (unsigned short*)d_ws;            // 1 plane (25.7 MB)
  unsigned short* W2F = aout + PLANE;                      // 49152 bf16 (frag order)
  unsigned short* W3 = W2F + 49152;                        // 16384 bf16
  float* BIASA = (float*)(W3 + 16384);                     // 4*4096 f32

  k_prep<<<36, 256, 0, stream>>>(qkv_w, out_w, rpe, W2F, W3, BIASA);
  k_fused<<<2048, 256, 0, stream>>>(x, W2F, qkv_b, BIASA, aout);
  k_gemm_out<<<1568, 256, 0, stream>>>(aout, W3, out_b, out);
}